// Round 3
// baseline (886.859 us; speedup 1.0000x reference)
//
#include <hip/hip_runtime.h>
#include <hip/hip_bf16.h>
#include <math.h>

#define B_SZ 1024
#define H_SZ 200
#define E_SZ 256
#define R_SZ 256
#define LN_EPS 1e-5f
#define NEG_HUGE -3.0e38f

typedef short bf16x8 __attribute__((ext_vector_type(8)));
typedef float f32x4 __attribute__((ext_vector_type(4)));

static __device__ __forceinline__ short f2bf(float f) {
  union { float f; unsigned u; } v; v.f = f;
  unsigned r = (v.u + 0x7fffu + ((v.u >> 16) & 1u)) >> 16;  // RNE
  return (short)(unsigned short)r;
}
static __device__ __forceinline__ float bf2f(unsigned short h) {
  union { unsigned u; float f; } v; v.u = ((unsigned)h) << 16; return v.f;
}
// XOR-swizzled fragment slot (16B units). Write: (q4f=k-quad, mf=row/col&15).
// Read: (q4f=lane>>4, mf=lane&15). Breaks the 16-way staging-store conflict.
static __device__ __forceinline__ int slotxor(int frame, int q4f, int mf, int ks) {
  return frame * 64 + (q4f << 4) + ((mf ^ (ks & 3) ^ ((q4f & 3) << 2)) & 15);
}
static __device__ __forceinline__ bf16x8 pack8(const float4& a, const float4& b) {
  bf16x8 v;
  v[0] = f2bf(a.x); v[1] = f2bf(a.y); v[2] = f2bf(a.z); v[3] = f2bf(a.w);
  v[4] = f2bf(b.x); v[5] = f2bf(b.y); v[6] = f2bf(b.z); v[7] = f2bf(b.w);
  return v;
}
static __device__ __forceinline__ float mask_at(const void* m, size_t idx, int is_b8) {
  if (is_b8) return ((const unsigned char*)m)[idx] ? 1.f : 0.f;
  return ((const int*)m)[idx] ? 1.f : 0.f;
}

// ---------------- K0: detect mask element width -----------------------------
__global__ void detect_mask_kernel(const unsigned char* __restrict__ mask,
                                   int* __restrict__ flag) {
  __shared__ int cnt;
  if (threadIdx.x == 0) cnt = 0;
  __syncthreads();
  int c = 0;
  for (int i = threadIdx.x; i < 4096; i += 256) c += mask[i] ? 1 : 0;
  atomicAdd(&cnt, c);
  __syncthreads();
  if (threadIdx.x == 0) *flag = (cnt > 2048) ? 1 : 0;
}

// ---------------- K0b: pre-swizzle W_rel into bf16 B-fragment order ---------
// Output layout: linear in slot index s; agg copies it LDS-linearly.
__global__ __launch_bounds__(256) void prep_wrel_kernel(
    const float* __restrict__ Wrel, short* __restrict__ Wg) {
  const int s = blockIdx.x * 256 + threadIdx.x;  // 0..8191
  const int frame = s >> 6, lf = s & 63, q4f = lf >> 4, mfx = lf & 15;
  const int ks = frame & 7, csub = frame >> 3;
  const int m = (mfx ^ (ks & 3) ^ ((q4f & 3) << 2)) & 15;  // xor is involutive
  const int e = csub * 16 + m;
  const int r0 = ks * 32 + q4f * 8;
  const float4* src = (const float4*)(Wrel + (size_t)e * R_SZ + r0);
  float4 a = src[0], b = src[1];
  *(bf16x8*)(Wg + (size_t)s * 8) = pack8(a, b);
}

// ---------------- K2: fused messages GEMM + decay + softmax + PNA -----------
// 256 blocks x 512 thr; block processes 4 b's. Deferred (non-online) softmax:
// per-tile msg kept packed-bf16 in registers, scores in LDS, softmax once.
#define AGG_LDS_BYTES 157200

__global__ __launch_bounds__(512, 2) void agg_kernel(
    const float* __restrict__ rel, const float* __restrict__ ent,
    const int* __restrict__ htime, const int* __restrict__ qtime,
    const void* __restrict__ mask, const int* __restrict__ mflag,
    const short* __restrict__ Wg, const float* __restrict__ qws,
    const float* __restrict__ e_emb, const float* __restrict__ log_gamma,
    float* __restrict__ comb) {
  extern __shared__ char smem[];
  short* Wsw = (short*)smem;                      //      0 .. 131072
  short* Asw = (short*)(smem + 131072);           // 131072 .. 147456
  float* maskf_s = (float*)(smem + 147456);       // 256 f
  float* decay_s = (float*)(smem + 148480);       // 256 f
  float* score_s = (float*)(smem + 149504);       // 256 f (scores -> p)
  float* s_part  = (float*)(smem + 150528);       // 224*4 f
  float* attn_acc = (float*)(smem + 154112);      // 256 f
  float* mean_b  = (float*)(smem + 155136);       // 256 f
  float* max_b   = (float*)(smem + 156160);       // 256 f
  float* scal    = (float*)(smem + 157184);       // {l, nv}

  const int t = threadIdx.x, lane = t & 63, w = t >> 6;
  const int rh = w >> 2, cg = w & 3, q4 = lane >> 4, cl = lane & 15;
  const float gamma = expf(log_gamma[0]);
  const int is_b8 = *mflag;

  // W stage: pure linear copy of pre-swizzled bf16 fragments
  {
    const bf16x8* src = (const bf16x8*)Wg;
    bf16x8* dst = (bf16x8*)Wsw;
#pragma unroll
    for (int p = 0; p < 16; ++p) dst[p * 512 + t] = src[p * 512 + t];
  }

  const int arow = t >> 4, rcc = t & 15;  // A staging coords (coalesced global)

  for (int bi = 0; bi < 4; ++bi) {
    const int b = blockIdx.x + 256 * bi;
    const int qt = qtime[b];
    if (t < 256) {
      attn_acc[t] = 0.f;
      float mf = 0.f, dc = 0.f;
      if (t < H_SZ) {
        mf = mask_at(mask, (size_t)b * H_SZ + t, is_b8);
        float td = fmaxf((float)(qt - htime[(size_t)b * H_SZ + t]), 0.f);
        dc = expf(-gamma * td);
      }
      maskf_s[t] = mf; decay_s[t] = dc;
    }
    float qv[4];
#pragma unroll
    for (int sub = 0; sub < 4; ++sub)
      qv[sub] = qws[(size_t)b * E_SZ + cg * 64 + sub * 16 + cl];

    // tile 0: A tile regs + ent regs, then frag-store A
    float4 c0, c1, c2, c3;
    {
      const int hc = min(arow, H_SZ - 1);
      const float4* src = (const float4*)(rel + ((size_t)b * H_SZ + hc) * R_SZ + rcc * 16);
      c0 = src[0]; c1 = src[1]; c2 = src[2]; c3 = src[3];
    }
    float entb[16];
#pragma unroll
    for (int reg = 0; reg < 4; ++reg) {
      const int hc = min(rh * 16 + q4 * 4 + reg, H_SZ - 1);
      const float* ep = ent + ((size_t)b * H_SZ + hc) * E_SZ + cg * 64 + cl;
#pragma unroll
      for (int sub = 0; sub < 4; ++sub) entb[reg * 4 + sub] = ep[sub * 16];
    }
    {
      const int rb = arow >> 4, m = arow & 15;
      bf16x8 v0 = pack8(c0, c1), v1 = pack8(c2, c3);
      int k8 = rcc * 2, ks = k8 >> 2, qw = k8 & 3;
      *(bf16x8*)(Asw + slotxor(rb * 8 + ks, qw, m, ks) * 8) = v0;
      k8 = rcc * 2 + 1; ks = k8 >> 2; qw = k8 & 3;
      *(bf16x8*)(Asw + slotxor(rb * 8 + ks, qw, m, ks) * 8) = v1;
    }
    __syncthreads();

    float mean4[4] = {0.f, 0.f, 0.f, 0.f};
    float max4[4] = {NEG_HUGE, NEG_HUGE, NEG_HUGE, NEG_HUGE};
    unsigned msgp[56];  // packed bf16 msg [tile][reg][subpair]

#pragma unroll
    for (int tile = 0; tile < 7; ++tile) {
      const int h0 = tile * 32;
      // prefetch next tile (rel + ent) into registers, clamped addresses
      float4 n0, n1, n2, n3;
      float entn[16];
      if (tile < 6) {
        const int hc = min(h0 + 32 + arow, H_SZ - 1);
        const float4* src = (const float4*)(rel + ((size_t)b * H_SZ + hc) * R_SZ + rcc * 16);
        n0 = src[0]; n1 = src[1]; n2 = src[2]; n3 = src[3];
#pragma unroll
        for (int reg = 0; reg < 4; ++reg) {
          const int hc2 = min(h0 + 32 + rh * 16 + q4 * 4 + reg, H_SZ - 1);
          const float* ep = ent + ((size_t)b * H_SZ + hc2) * E_SZ + cg * 64 + cl;
#pragma unroll
          for (int sub = 0; sub < 4; ++sub) entn[reg * 4 + sub] = ep[sub * 16];
        }
      }
      // MFMA: 32 rows x 256 e
      f32x4 acc[4] = {};
#pragma unroll
      for (int ks = 0; ks < 8; ++ks) {
        bf16x8 av = *(const bf16x8*)(Asw + slotxor(rh * 8 + ks, q4, cl, ks) * 8);
#pragma unroll
        for (int sub = 0; sub < 4; ++sub) {
          bf16x8 bv = *(const bf16x8*)(Wsw + slotxor((cg * 4 + sub) * 8 + ks, q4, cl, ks) * 8);
          acc[sub] = __builtin_amdgcn_mfma_f32_16x16x32_bf16(av, bv, acc[sub], 0, 0, 0);
        }
      }
      // epilogue: msg, mean/max partials, score partials
      float sc[4];
#pragma unroll
      for (int reg = 0; reg < 4; ++reg) {
        const int row = rh * 16 + q4 * 4 + reg;
        const int hg = h0 + row;
        const float mf = maskf_s[hg];
        const bool rr = hg < H_SZ;
        float srow = 0.f, mtmp[4];
#pragma unroll
        for (int sub = 0; sub < 4; ++sub) {
          float m = rr ? acc[sub][reg] * entb[reg * 4 + sub] : 0.f;
          mtmp[sub] = m;
          mean4[sub] += mf * m;
          float cand = rr ? (mf != 0.f ? m : 0.f) : NEG_HUGE;
          max4[sub] = fmaxf(max4[sub], cand);
          srow += qv[sub] * m;
        }
        sc[reg] = srow;
        msgp[tile * 8 + reg * 2 + 0] =
            (unsigned)(unsigned short)f2bf(mtmp[0]) | ((unsigned)(unsigned short)f2bf(mtmp[1]) << 16);
        msgp[tile * 8 + reg * 2 + 1] =
            (unsigned)(unsigned short)f2bf(mtmp[2]) | ((unsigned)(unsigned short)f2bf(mtmp[3]) << 16);
      }
#pragma unroll
      for (int mm = 1; mm <= 8; mm <<= 1)
#pragma unroll
        for (int reg = 0; reg < 4; ++reg) sc[reg] += __shfl_xor(sc[reg], mm, 64);
      if (cl == 0)
#pragma unroll
        for (int reg = 0; reg < 4; ++reg)
          s_part[(h0 + rh * 16 + q4 * 4 + reg) * 4 + cg] = sc[reg];

      if (tile < 6) {
#pragma unroll
        for (int i = 0; i < 16; ++i) entb[i] = entn[i];
        __syncthreads();  // all waves done reading Asw(tile)
        const int rb = arow >> 4, m = arow & 15;
        bf16x8 v0 = pack8(n0, n1), v1 = pack8(n2, n3);
        int k8 = rcc * 2, ks = k8 >> 2, qw = k8 & 3;
        *(bf16x8*)(Asw + slotxor(rb * 8 + ks, qw, m, ks) * 8) = v0;
        k8 = rcc * 2 + 1; ks = k8 >> 2; qw = k8 & 3;
        *(bf16x8*)(Asw + slotxor(rb * 8 + ks, qw, m, ks) * 8) = v1;
        __syncthreads();  // writes visible
      }
    }  // tiles
    __syncthreads();  // last tile's s_part visible

    // ---- softmax (once) ----
    if (t < 256) {
      float s = NEG_HUGE;
      if (t < H_SZ) {
        float srow = s_part[t * 4] + s_part[t * 4 + 1] + s_part[t * 4 + 2] + s_part[t * 4 + 3];
        s = (maskf_s[t] != 0.f) ? decay_s[t] * srow * 0.0625f : -1e9f;
      }
      score_s[t] = s;
    }
    __syncthreads();
    if (w == 0) {
      float s0 = score_s[lane], s1 = score_s[lane + 64];
      float s2 = score_s[lane + 128], s3 = score_s[lane + 192];
      float mv = fmaxf(fmaxf(s0, s1), fmaxf(s2, s3));
#pragma unroll
      for (int mm = 1; mm <= 32; mm <<= 1) mv = fmaxf(mv, __shfl_xor(mv, mm, 64));
      float e0 = expf(s0 - mv), e1 = expf(s1 - mv), e2 = expf(s2 - mv), e3 = expf(s3 - mv);
      score_s[lane] = e0; score_s[lane + 64] = e1;
      score_s[lane + 128] = e2; score_s[lane + 192] = e3;
      float ls = e0 + e1 + e2 + e3;
      float nv = maskf_s[lane] + maskf_s[lane + 64] + maskf_s[lane + 128] + maskf_s[lane + 192];
#pragma unroll
      for (int mm = 1; mm <= 32; mm <<= 1) {
        ls += __shfl_xor(ls, mm, 64);
        nv += __shfl_xor(nv, mm, 64);
      }
      if (lane == 0) { scal[0] = ls; scal[1] = nv; }
    }
    __syncthreads();

    // ---- attn accumulation from register msg ----
    float av4[4] = {0.f, 0.f, 0.f, 0.f};
#pragma unroll
    for (int tile = 0; tile < 7; ++tile)
#pragma unroll
      for (int reg = 0; reg < 4; ++reg) {
        float p = score_s[tile * 32 + rh * 16 + q4 * 4 + reg];
        unsigned pa = msgp[tile * 8 + reg * 2], pb = msgp[tile * 8 + reg * 2 + 1];
        av4[0] += p * bf2f((unsigned short)(pa & 0xffff));
        av4[1] += p * bf2f((unsigned short)(pa >> 16));
        av4[2] += p * bf2f((unsigned short)(pb & 0xffff));
        av4[3] += p * bf2f((unsigned short)(pb >> 16));
      }
#pragma unroll
    for (int sub = 0; sub < 4; ++sub) {
      av4[sub] += __shfl_xor(av4[sub], 16, 64);
      av4[sub] += __shfl_xor(av4[sub], 32, 64);
    }
    if (q4 == 0)
#pragma unroll
      for (int sub = 0; sub < 4; ++sub)
        atomicAdd(&attn_acc[cg * 64 + sub * 16 + cl], av4[sub]);

    // ---- mean/max cross-lane + cross-wave reduce ----
#pragma unroll
    for (int sub = 0; sub < 4; ++sub) {
      mean4[sub] += __shfl_xor(mean4[sub], 16, 64);
      mean4[sub] += __shfl_xor(mean4[sub], 32, 64);
      max4[sub] = fmaxf(max4[sub], __shfl_xor(max4[sub], 16, 64));
      max4[sub] = fmaxf(max4[sub], __shfl_xor(max4[sub], 32, 64));
    }
    if (rh == 0 && q4 == 0)
#pragma unroll
      for (int sub = 0; sub < 4; ++sub) {
        mean_b[cg * 64 + sub * 16 + cl] = mean4[sub];
        max_b[cg * 64 + sub * 16 + cl] = max4[sub];
      }
    __syncthreads();
    if (rh == 1 && q4 == 0)
#pragma unroll
      for (int sub = 0; sub < 4; ++sub) {
        const int e = cg * 64 + sub * 16 + cl;
        mean_b[e] += mean4[sub];
        max_b[e] = fmaxf(max_b[e], max4[sub]);
      }
    __syncthreads();
    if (t < 256) {
      const float nv = fmaxf(scal[1], 1.f), l = scal[0];
      float* dst = comb + (size_t)b * 1024;
      dst[t] = mean_b[t] / nv;
      dst[256 + t] = max_b[t];
      dst[512 + t] = attn_acc[t] / l;
      dst[768 + t] = e_emb[(size_t)b * E_SZ + t];
    }
    __syncthreads();
  }  // bi
}

// ---------------- K3: generic 64x64-tile bf16 MFMA GEMM, C = A @ W^T --------
// A: M x K fp32, W: N x K fp32, C: M x N fp32. grid (M/64, N/64), 256 thr.
template <int N, int K>
__global__ __launch_bounds__(256) void gemm_bf16(const float* __restrict__ A,
                                                 const float* __restrict__ W,
                                                 float* __restrict__ C) {
  __shared__ short As[2][4096];
  __shared__ short Ws[2][4096];
  const int t = threadIdx.x, lane = t & 63, w = t >> 6, q4 = lane >> 4, cl = lane & 15;
  const int row0 = blockIdx.x * 64, col0 = blockIdx.y * 64;
  const int sr = t >> 2, kc = t & 3;
  const int rb = sr >> 4, sm = sr & 15;
  constexpr int KT = K / 64;

  float4 ar[4], wr4[4];
  {
    const float4* ap = (const float4*)(A + (size_t)(row0 + sr) * K + kc * 16);
    const float4* wp = (const float4*)(W + (size_t)(col0 + sr) * K + kc * 16);
    ar[0] = ap[0]; ar[1] = ap[1]; ar[2] = ap[2]; ar[3] = ap[3];
    wr4[0] = wp[0]; wr4[1] = wp[1]; wr4[2] = wp[2]; wr4[3] = wp[3];
  }
  {
    bf16x8 a0 = pack8(ar[0], ar[1]), a1 = pack8(ar[2], ar[3]);
    bf16x8 b0 = pack8(wr4[0], wr4[1]), b1 = pack8(wr4[2], wr4[3]);
    int k8 = kc * 2, ks = k8 >> 2, qw = k8 & 3;
    *(bf16x8*)&As[0][slotxor(rb * 2 + ks, qw, sm, ks) * 8] = a0;
    *(bf16x8*)&Ws[0][slotxor(rb * 2 + ks, qw, sm, ks) * 8] = b0;
    k8 = kc * 2 + 1; ks = k8 >> 2; qw = k8 & 3;
    *(bf16x8*)&As[0][slotxor(rb * 2 + ks, qw, sm, ks) * 8] = a1;
    *(bf16x8*)&Ws[0][slotxor(rb * 2 + ks, qw, sm, ks) * 8] = b1;
  }
  __syncthreads();

  f32x4 acc[4] = {};
  for (int kt = 0; kt < KT; ++kt) {
    if (kt + 1 < KT) {
      const float4* ap = (const float4*)(A + (size_t)(row0 + sr) * K + (kt + 1) * 64 + kc * 16);
      const float4* wp = (const float4*)(W + (size_t)(col0 + sr) * K + (kt + 1) * 64 + kc * 16);
      ar[0] = ap[0]; ar[1] = ap[1]; ar[2] = ap[2]; ar[3] = ap[3];
      wr4[0] = wp[0]; wr4[1] = wp[1]; wr4[2] = wp[2]; wr4[3] = wp[3];
    }
    const short* Ab = As[kt & 1];
    const short* Wb = Ws[kt & 1];
#pragma unroll
    for (int ks = 0; ks < 2; ++ks) {
      bf16x8 av = *(const bf16x8*)&Ab[slotxor(w * 2 + ks, q4, cl, ks) * 8];
#pragma unroll
      for (int cb = 0; cb < 4; ++cb) {
        bf16x8 bv = *(const bf16x8*)&Wb[slotxor(cb * 2 + ks, q4, cl, ks) * 8];
        acc[cb] = __builtin_amdgcn_mfma_f32_16x16x32_bf16(av, bv, acc[cb], 0, 0, 0);
      }
    }
    if (kt + 1 < KT) {
      short* An = (short*)As[(kt + 1) & 1];
      short* Wn = (short*)Ws[(kt + 1) & 1];
      bf16x8 a0 = pack8(ar[0], ar[1]), a1 = pack8(ar[2], ar[3]);
      bf16x8 b0 = pack8(wr4[0], wr4[1]), b1 = pack8(wr4[2], wr4[3]);
      int k8 = kc * 2, ks = k8 >> 2, qw = k8 & 3;
      *(bf16x8*)&An[slotxor(rb * 2 + ks, qw, sm, ks) * 8] = a0;
      *(bf16x8*)&Wn[slotxor(rb * 2 + ks, qw, sm, ks) * 8] = b0;
      k8 = kc * 2 + 1; ks = k8 >> 2; qw = k8 & 3;
      *(bf16x8*)&An[slotxor(rb * 2 + ks, qw, sm, ks) * 8] = a1;
      *(bf16x8*)&Wn[slotxor(rb * 2 + ks, qw, sm, ks) * 8] = b1;
    }
    __syncthreads();
  }
#pragma unroll
  for (int cb = 0; cb < 4; ++cb)
#pragma unroll
    for (int reg = 0; reg < 4; ++reg) {
      const int rowi = row0 + w * 16 + q4 * 4 + reg;
      const int coli = col0 + cb * 16 + cl;
      C[(size_t)rowi * N + coli] = acc[cb][reg];
    }
}

// ---------------- K4: bias + LayerNorm (+ exact GELU) -----------------------
template <int N, bool G>
__global__ __launch_bounds__(256) void ln_kernel(const float* __restrict__ pre,
                                                 const float* __restrict__ bias,
                                                 const float* __restrict__ gg,
                                                 const float* __restrict__ bb,
                                                 float* __restrict__ out) {
  constexpr int CPT = N / 256;
  __shared__ float red[2][4];
  __shared__ float mr[2];
  const int t = threadIdx.x, lane = t & 63, w = t >> 6;
  const size_t row = blockIdx.x;
  float v[CPT];
  float s = 0.f, s2 = 0.f;
#pragma unroll
  for (int i = 0; i < CPT; ++i) {
    const int c = t + 256 * i;
    v[i] = pre[row * N + c] + bias[c];
    s += v[i]; s2 += v[i] * v[i];
  }
#pragma unroll
  for (int mm = 1; mm <= 32; mm <<= 1) {
    s += __shfl_xor(s, mm, 64);
    s2 += __shfl_xor(s2, mm, 64);
  }
  if (lane == 0) { red[0][w] = s; red[1][w] = s2; }
  __syncthreads();
  if (t == 0) {
    float a = red[0][0] + red[0][1] + red[0][2] + red[0][3];
    float q = red[1][0] + red[1][1] + red[1][2] + red[1][3];
    mr[0] = a / N; mr[1] = q / N;
  }
  __syncthreads();
  const float mu = mr[0];
  const float var = fmaxf(mr[1] - mu * mu, 0.f);
  const float rstd = rsqrtf(var + LN_EPS);
#pragma unroll
  for (int i = 0; i < CPT; ++i) {
    const int c = t + 256 * i;
    float x = (v[i] - mu) * rstd * gg[c] + bb[c];
    if (G) x = 0.5f * x * (1.f + erff(x * 0.70710678118654752f));
    out[row * N + c] = x;
  }
}

extern "C" void kernel_launch(void* const* d_in, const int* in_sizes, int n_in,
                              void* d_out, int out_size, void* d_ws,
                              size_t ws_size, hipStream_t stream) {
  const float* e_emb = (const float*)d_in[0];
  const float* ent = (const float*)d_in[1];
  const float* rel = (const float*)d_in[2];
  const int* ht = (const int*)d_in[3];
  const int* qt = (const int*)d_in[4];
  const void* mask = d_in[5];
  const float* Wrel = (const float*)d_in[6];
  const float* Wq = (const float*)d_in[7];
  const float* lg = (const float*)d_in[8];
  const float* W1 = (const float*)d_in[9];
  const float* b1 = (const float*)d_in[10];
  const float* ln1g = (const float*)d_in[11];
  const float* ln1b = (const float*)d_in[12];
  const float* W2 = (const float*)d_in[13];
  const float* b2 = (const float*)d_in[14];
  const float* ln2g = (const float*)d_in[15];
  const float* ln2b = (const float*)d_in[16];
  const float* Wc = (const float*)d_in[17];
  const float* bc = (const float*)d_in[18];
  const float* lncg = (const float*)d_in[19];
  const float* lncb = (const float*)d_in[20];

  // Workspace overlay (<= 7 MB, lifetime-disjoint reuse):
  float* q_ws = (float*)d_ws;                             // 0..1MB   (dead after agg)
  float* comb = (float*)((char*)d_ws + (1 << 20));        // 1..5MB   (dead after gemm1)
  float* t1   = (float*)((char*)d_ws + (1 << 20));        // 1..3MB   (after comb dead)
  float* prec = (float*)((char*)d_ws + (3 << 20));        // 3..5MB   (after t1 dead)
  float* pre1 = (float*)((char*)d_ws + (5 << 20));        // 5..7MB   (after Wg dead)
  float* pre2 = q_ws;                                     // 0..1MB   (after q dead)
  short* Wg   = (short*)((char*)d_ws + (5 << 20));        // 5..5.125MB (dead after agg)
  int* mflag  = (int*)((char*)d_ws + (5 << 20) + 131072); // inside pre1 region, read pre-gemm1
  float* dyn = (float*)d_out;                             // B x 256
  float* ctx = (float*)d_out + (size_t)B_SZ * E_SZ;       // B x 512

  (void)hipFuncSetAttribute((const void*)agg_kernel,
                            hipFuncAttributeMaxDynamicSharedMemorySize,
                            AGG_LDS_BYTES);

  detect_mask_kernel<<<1, 256, 0, stream>>>((const unsigned char*)mask, mflag);
  prep_wrel_kernel<<<32, 256, 0, stream>>>(Wrel, Wg);
  gemm_bf16<256, 256><<<dim3(16, 4), 256, 0, stream>>>(e_emb, Wq, q_ws);
  agg_kernel<<<256, 512, AGG_LDS_BYTES, stream>>>(rel, ent, ht, qt, mask, mflag,
                                                  Wg, q_ws, e_emb, lg, comb);
  gemm_bf16<512, 1024><<<dim3(16, 8), 256, 0, stream>>>(comb, W1, pre1);
  ln_kernel<512, true><<<1024, 256, 0, stream>>>(pre1, b1, ln1g, ln1b, t1);
  gemm_bf16<256, 512><<<dim3(16, 4), 256, 0, stream>>>(t1, W2, pre2);
  ln_kernel<256, false><<<1024, 256, 0, stream>>>(pre2, b2, ln2g, ln2b, dyn);
  gemm_bf16<512, 256><<<dim3(16, 8), 256, 0, stream>>>(dyn, Wc, prec);
  ln_kernel<512, true><<<1024, 256, 0, stream>>>(prec, bc, lncg, lncb, ctx);
}